// Round 1
// baseline (821.812 us; speedup 1.0000x reference)
//
#include <hip/hip_runtime.h>

#define SCALE 0.17677669529663687f   // 1/sqrt(32)
#define GAIN  0.0625f                // 1/sqrt(256)

typedef float f32x4 __attribute__((ext_vector_type(4)));
typedef short s16x8 __attribute__((ext_vector_type(8)));
typedef short s16x4 __attribute__((ext_vector_type(4)));

static __device__ __forceinline__ short f2bf(float f) {
  union { float f; unsigned u; } v; v.f = f;
  unsigned u = v.u;
  u += 0x7fffu + ((u >> 16) & 1u);   // round-to-nearest-even
  return (short)(u >> 16);
}

__global__ void prep_weights(const float* __restrict__ qw, const float* __restrict__ kw,
                             const float* __restrict__ vw, const float* __restrict__ pw,
                             short* __restrict__ wsb) {
  int i = blockIdx.x * 256 + threadIdx.x;   // 0..65535
  wsb[i]          = f2bf(qw[i] * GAIN);
  wsb[i + 65536]  = f2bf(kw[i] * GAIN);
  wsb[i + 131072] = f2bf(vw[i] * GAIN);
  wsb[i + 196608] = f2bf(pw[i] * GAIN);
}

// ---- LDS layout (bytes) ----
// per-wave QK region: LQ[64][72] + LK[64][72] bf16 (9216 B each); later aliased by P[2][64][72]
#define OFF_QK   0        // 4 * 18432 = 73728
#define OFF_LV   73728    // 4 * 9216  = 36864   LV[64 d][72 m] bf16 per wave
#define OFF_MASK 110592   // f32 [64][68] = 17408
#define OFF_A    128000   // bf16 [64][264] = 33792  (attn out, token-major)
#define OFF_INV  161792   // f32 [64]
#define OFF_PART 162048   // f32 [64][4]
#define LDS_TOTAL 163072

template<bool BF16W>
__global__ __launch_bounds__(256, 1)
void wattn(const float* __restrict__ x, const float* __restrict__ mask,
           const float* __restrict__ qw, const float* __restrict__ qb,
           const float* __restrict__ kw, const float* __restrict__ kb,
           const float* __restrict__ vw, const float* __restrict__ vb,
           const float* __restrict__ pw, const float* __restrict__ pb,
           const short* __restrict__ wsb, float* __restrict__ out)
{
  __shared__ __align__(16) char smem[LDS_TOTAL];
  const int tid  = threadIdx.x;
  const int lane = tid & 63;
  const int w    = tid >> 6;     // wave 0..3
  const int c    = lane & 15;
  const int g    = lane >> 4;    // 0..3
  const int cs   = w * 64;       // wave's column slice (2 heads)
  const int b    = blockIdx.x;

  const float* xg = x + (size_t)b * (64 * 256);
  float* mask_lds = (float*)(smem + OFF_MASK);
  float* inv_lds  = (float*)(smem + OFF_INV);
  float* part_lds = (float*)(smem + OFF_PART);
  short* LQ = (short*)(smem + OFF_QK) + w * 9216;   // shorts: 18432B/2 per wave
  short* LK = LQ + 4608;
  short* LV = (short*)(smem + OFF_LV) + w * 4608;
  short* Pb = LQ;                                    // P[2][64][72] aliases LQ+LK
  short* La = (short*)(smem + OFF_A);

  const short* wq_bf = wsb;
  const short* wk_bf = wsb + 65536;
  const short* wv_bf = wsb + 131072;
  const short* wp_bf = wsb + 196608;

  // ---- stage mask (coalesced) ----
  {
    const float* mg = mask + (size_t)b * (64 * 64);
    int r0 = tid >> 2, q4 = (tid & 3) * 16;
    const f32x4* src = (const f32x4*)(mg + r0 * 64 + q4);
    f32x4* dst = (f32x4*)(mask_lds + r0 * 68 + q4);
#pragma unroll
    for (int u = 0; u < 4; ++u) dst[u] = src[u];
  }
  // ---- row norms ----
  {
    int r0 = tid >> 2, q64 = (tid & 3) * 64;
    const f32x4* xr = (const f32x4*)(xg + r0 * 256 + q64);
    float ss = 0.f;
#pragma unroll
    for (int u = 0; u < 16; ++u) { f32x4 v = xr[u]; ss += v[0]*v[0] + v[1]*v[1] + v[2]*v[2] + v[3]*v[3]; }
    part_lds[r0 * 4 + (tid & 3)] = ss;
  }
  __syncthreads();
  if (tid < 64) {
    float s = part_lds[tid*4] + part_lds[tid*4+1] + part_lds[tid*4+2] + part_lds[tid*4+3];
    inv_lds[tid] = 1.0f / fmaxf(sqrtf(s), 1e-12f);
  }
  __syncthreads();

  // fragment loaders
  auto wfrag = [&](const short* wbf, const float* wf, int row, int k0) -> s16x8 {
    s16x8 r;
    if constexpr (BF16W) {
      r = *(const s16x8*)(wbf + row * 256 + k0);
    } else {
      const f32x4* p = (const f32x4*)(wf + row * 256 + k0);
      f32x4 a = p[0], b2 = p[1];
#pragma unroll
      for (int j = 0; j < 4; ++j) { r[j] = f2bf(a[j] * GAIN); r[j+4] = f2bf(b2[j] * GAIN); }
    }
    return r;
  };
  auto xfrag = [&](int row, int k0, float scl) -> s16x8 {
    const f32x4* p = (const f32x4*)(xg + row * 256 + k0);
    f32x4 a = p[0], b2 = p[1];
    s16x8 r;
#pragma unroll
    for (int j = 0; j < 4; ++j) { r[j] = f2bf(a[j] * scl); r[j+4] = f2bf(b2[j] * scl); }
    return r;
  };

  float fn[4];
#pragma unroll
  for (int ni = 0; ni < 4; ++ni) fn[ni] = inv_lds[16*ni + c];

  // ---- Q projection (computes Q^T: A=Wq slice, B=norm_x) -> LQ[n][d] ----
  {
    f32x4 acc[4][4] = {};
#pragma unroll
    for (int kk = 0; kk < 8; ++kk) {
      const int k0 = kk*32 + g*8;
      s16x8 bf[4], af[4];
#pragma unroll
      for (int ni = 0; ni < 4; ++ni) bf[ni] = xfrag(16*ni + c, k0, fn[ni]);
#pragma unroll
      for (int mi = 0; mi < 4; ++mi) af[mi] = wfrag(wq_bf, qw, cs + 16*mi + c, k0);
#pragma unroll
      for (int mi = 0; mi < 4; ++mi)
#pragma unroll
        for (int ni = 0; ni < 4; ++ni)
          acc[mi][ni] = __builtin_amdgcn_mfma_f32_16x16x32_bf16(af[mi], bf[ni], acc[mi][ni], 0, 0, 0);
    }
#pragma unroll
    for (int mi = 0; mi < 4; ++mi) {
      float bq[4];
#pragma unroll
      for (int r = 0; r < 4; ++r) bq[r] = qb[cs + 16*mi + 4*g + r];
#pragma unroll
      for (int ni = 0; ni < 4; ++ni) {
        s16x4 pk;
#pragma unroll
        for (int r = 0; r < 4; ++r) pk[r] = f2bf(acc[mi][ni][r] + bq[r]);
        *(s16x4*)(LQ + (16*ni + c)*72 + 16*mi + 4*g) = pk;
      }
    }
  }
  // ---- K projection -> LK[m][d] ----
  {
    f32x4 acc[4][4] = {};
#pragma unroll
    for (int kk = 0; kk < 8; ++kk) {
      const int k0 = kk*32 + g*8;
      s16x8 bf[4], af[4];
#pragma unroll
      for (int ni = 0; ni < 4; ++ni) bf[ni] = xfrag(16*ni + c, k0, fn[ni]);
#pragma unroll
      for (int mi = 0; mi < 4; ++mi) af[mi] = wfrag(wk_bf, kw, cs + 16*mi + c, k0);
#pragma unroll
      for (int mi = 0; mi < 4; ++mi)
#pragma unroll
        for (int ni = 0; ni < 4; ++ni)
          acc[mi][ni] = __builtin_amdgcn_mfma_f32_16x16x32_bf16(af[mi], bf[ni], acc[mi][ni], 0, 0, 0);
    }
#pragma unroll
    for (int mi = 0; mi < 4; ++mi) {
      float bk[4];
#pragma unroll
      for (int r = 0; r < 4; ++r) bk[r] = kb[cs + 16*mi + 4*g + r];
#pragma unroll
      for (int ni = 0; ni < 4; ++ni) {
        s16x4 pk;
#pragma unroll
        for (int r = 0; r < 4; ++r) pk[r] = f2bf(acc[mi][ni][r] + bk[r]);
        *(s16x4*)(LK + (16*ni + c)*72 + 16*mi + 4*g) = pk;
      }
    }
  }
  // ---- V projection (standard: A=x rows, B=Wv slice) -> LV[d][m] (transposed store) ----
  {
    f32x4 acc[4][4] = {};
#pragma unroll
    for (int kk = 0; kk < 8; ++kk) {
      const int k0 = kk*32 + g*8;
      s16x8 af[4], bf[4];
#pragma unroll
      for (int mi = 0; mi < 4; ++mi) af[mi] = xfrag(16*mi + c, k0, 1.0f);
#pragma unroll
      for (int ni = 0; ni < 4; ++ni) bf[ni] = wfrag(wv_bf, vw, cs + 16*ni + c, k0);
#pragma unroll
      for (int mi = 0; mi < 4; ++mi)
#pragma unroll
        for (int ni = 0; ni < 4; ++ni)
          acc[mi][ni] = __builtin_amdgcn_mfma_f32_16x16x32_bf16(af[mi], bf[ni], acc[mi][ni], 0, 0, 0);
    }
    float bv[4];
#pragma unroll
    for (int ni = 0; ni < 4; ++ni) bv[ni] = vb[cs + 16*ni + c];
#pragma unroll
    for (int mi = 0; mi < 4; ++mi)
#pragma unroll
      for (int ni = 0; ni < 4; ++ni) {
        s16x4 pk;
#pragma unroll
        for (int r = 0; r < 4; ++r) pk[r] = f2bf(acc[mi][ni][r] + bv[ni]);
        *(s16x4*)(LV + (16*ni + c)*72 + 16*mi + 4*g) = pk;
      }
  }

  // ---- attention: both heads' logits first (LQ/LK die before P alias-writes) ----
  f32x4 al[2][4][4];
  const f32x4 zf = {0.f, 0.f, 0.f, 0.f};
#pragma unroll
  for (int h2 = 0; h2 < 2; ++h2) {
    const int hb = 32 * h2;
    s16x8 qf[4], kf[4];
#pragma unroll
    for (int mi = 0; mi < 4; ++mi) qf[mi] = *(const s16x8*)(LQ + (16*mi + c)*72 + hb + 8*g);
#pragma unroll
    for (int ni = 0; ni < 4; ++ni) kf[ni] = *(const s16x8*)(LK + (16*ni + c)*72 + hb + 8*g);
#pragma unroll
    for (int mi = 0; mi < 4; ++mi)
#pragma unroll
      for (int ni = 0; ni < 4; ++ni)
        al[h2][mi][ni] = __builtin_amdgcn_mfma_f32_16x16x32_bf16(qf[mi], kf[ni], zf, 0, 0, 0);
  }
  // ---- softmax (rows n = 16mi+4g+r; cols across ni and 16 lanes) + P write ----
#pragma unroll
  for (int h2 = 0; h2 < 2; ++h2) {
#pragma unroll
    for (int mi = 0; mi < 4; ++mi) {
      float mx[4] = {-1e30f, -1e30f, -1e30f, -1e30f};
#pragma unroll
      for (int ni = 0; ni < 4; ++ni)
#pragma unroll
        for (int r = 0; r < 4; ++r) {
          float l = al[h2][mi][ni][r] * SCALE + mask_lds[(16*mi + 4*g + r)*68 + 16*ni + c];
          al[h2][mi][ni][r] = l;
          mx[r] = fmaxf(mx[r], l);
        }
#pragma unroll
      for (int r = 0; r < 4; ++r)
#pragma unroll
        for (int d = 1; d < 16; d <<= 1) mx[r] = fmaxf(mx[r], __shfl_xor(mx[r], d, 64));
      float sm[4] = {0.f, 0.f, 0.f, 0.f};
#pragma unroll
      for (int ni = 0; ni < 4; ++ni)
#pragma unroll
        for (int r = 0; r < 4; ++r) {
          float e = __expf(al[h2][mi][ni][r] - mx[r]);
          al[h2][mi][ni][r] = e;
          sm[r] += e;
        }
#pragma unroll
      for (int r = 0; r < 4; ++r)
#pragma unroll
        for (int d = 1; d < 16; d <<= 1) sm[r] += __shfl_xor(sm[r], d, 64);
      float rs[4];
#pragma unroll
      for (int r = 0; r < 4; ++r) rs[r] = 1.0f / sm[r];
#pragma unroll
      for (int ni = 0; ni < 4; ++ni)
#pragma unroll
        for (int r = 0; r < 4; ++r)
          Pb[h2*4608 + (16*mi + 4*g + r)*72 + 16*ni + c] = f2bf(al[h2][mi][ni][r] * rs[r]);
    }
  }
  // ---- PV (computes out^T per head: A=V^T from LV, B=P^T) -> La[n][j] ----
#pragma unroll
  for (int h2 = 0; h2 < 2; ++h2) {
    const int hb = 32 * h2;
    f32x4 acc[2][4] = {};
#pragma unroll
    for (int kk = 0; kk < 2; ++kk) {
      const int k0 = kk*32 + 8*g;
      s16x8 vf[2], pf[4];
#pragma unroll
      for (int mi = 0; mi < 2; ++mi) vf[mi] = *(const s16x8*)(LV + (hb + 16*mi + c)*72 + k0);
#pragma unroll
      for (int ni = 0; ni < 4; ++ni) pf[ni] = *(const s16x8*)(Pb + h2*4608 + (16*ni + c)*72 + k0);
#pragma unroll
      for (int mi = 0; mi < 2; ++mi)
#pragma unroll
        for (int ni = 0; ni < 4; ++ni)
          acc[mi][ni] = __builtin_amdgcn_mfma_f32_16x16x32_bf16(vf[mi], pf[ni], acc[mi][ni], 0, 0, 0);
    }
#pragma unroll
    for (int mi = 0; mi < 2; ++mi)
#pragma unroll
      for (int ni = 0; ni < 4; ++ni) {
        s16x4 pk;
#pragma unroll
        for (int r = 0; r < 4; ++r) pk[r] = f2bf(acc[mi][ni][r]);
        *(s16x4*)(La + (16*ni + c)*264 + cs + hb + 16*mi + 4*g) = pk;
      }
  }
  __syncthreads();

  // ---- final projection: O[n,i] = a @ Wp^T + pb ----
  {
    f32x4 acc[4][4] = {};
#pragma unroll
    for (int kk = 0; kk < 8; ++kk) {
      const int k0 = kk*32 + 8*g;
      s16x8 af[4], bf[4];
#pragma unroll
      for (int mi = 0; mi < 4; ++mi) af[mi] = *(const s16x8*)(La + (16*mi + c)*264 + k0);
#pragma unroll
      for (int ni = 0; ni < 4; ++ni) bf[ni] = wfrag(wp_bf, pw, cs + 16*ni + c, k0);
#pragma unroll
      for (int mi = 0; mi < 4; ++mi)
#pragma unroll
        for (int ni = 0; ni < 4; ++ni)
          acc[mi][ni] = __builtin_amdgcn_mfma_f32_16x16x32_bf16(af[mi], bf[ni], acc[mi][ni], 0, 0, 0);
    }
    float bp[4];
#pragma unroll
    for (int ni = 0; ni < 4; ++ni) bp[ni] = pb[cs + 16*ni + c];
    float* og = out + (size_t)b * (64 * 256);
#pragma unroll
    for (int mi = 0; mi < 4; ++mi)
#pragma unroll
      for (int ni = 0; ni < 4; ++ni)
#pragma unroll
        for (int r = 0; r < 4; ++r)
          og[(16*mi + 4*g + r)*256 + cs + 16*ni + c] = acc[mi][ni][r] + bp[ni];
  }
}

extern "C" void kernel_launch(void* const* d_in, const int* in_sizes, int n_in,
                              void* d_out, int out_size, void* d_ws, size_t ws_size,
                              hipStream_t stream) {
  const float* x    = (const float*)d_in[0];
  const float* mask = (const float*)d_in[1];
  const float* qw   = (const float*)d_in[2];
  const float* qb   = (const float*)d_in[3];
  const float* kw   = (const float*)d_in[4];
  const float* kb   = (const float*)d_in[5];
  const float* vw   = (const float*)d_in[6];
  const float* vb   = (const float*)d_in[7];
  const float* pw   = (const float*)d_in[8];
  const float* pb   = (const float*)d_in[9];
  float* out = (float*)d_out;

  if (ws_size >= 4u * 65536u * sizeof(short)) {
    short* wsb = (short*)d_ws;
    prep_weights<<<256, 256, 0, stream>>>(qw, kw, vw, pw, wsb);
    wattn<true><<<4096, 256, 0, stream>>>(x, mask, qw, qb, kw, kb, vw, vb, pw, pb, wsb, out);
  } else {
    wattn<false><<<4096, 256, 0, stream>>>(x, mask, qw, qb, kw, kb, vw, vb, pw, pb, nullptr, out);
  }
}

// Round 3
// 497.526 us; speedup vs baseline: 1.6518x; 1.6518x over previous
//
#include <hip/hip_runtime.h>

#define SCALE 0.17677669529663687f   // 1/sqrt(32)
#define GAIN  0.0625f                // 1/sqrt(256)

typedef float f32x4 __attribute__((ext_vector_type(4)));
typedef short s16x8 __attribute__((ext_vector_type(8)));
typedef short s16x4 __attribute__((ext_vector_type(4)));

static __device__ __forceinline__ short f2bf(float f) {
  union { float f; unsigned u; } v; v.f = f;
  unsigned u = v.u;
  u += 0x7fffu + ((u >> 16) & 1u);   // RNE
  return (short)(u >> 16);
}

__global__ void prep_weights(const float* __restrict__ qw, const float* __restrict__ kw,
                             const float* __restrict__ vw, const float* __restrict__ pw,
                             short* __restrict__ wsb) {
  int i = blockIdx.x * 256 + threadIdx.x;   // 0..65535
  wsb[i]          = f2bf(qw[i] * GAIN);
  wsb[i + 65536]  = f2bf(kw[i] * GAIN);
  wsb[i + 131072] = f2bf(vw[i] * GAIN);
  wsb[i + 196608] = f2bf(pw[i] * GAIN);
}

// ---- LDS layout (bytes) ----
// XN/Q/K: bf16 [64 tokens][264] (row stride 528B, 16B-aligned, 4c-bank pattern)
// V: bf16 [256 d][72 tokens]; ML: f32 [64][68]; SN: f32[64]
// Aliases: P[h] ([64][72] bf16, 9216B): heads 0..6 at byte h*9216 (over dead XN+Q),
//          head 7 over dead ML. AN [64][264] over dead K.
#define OFF_XN 0
#define OFF_Q  33792
#define OFF_K  67584
#define OFF_V  101376
#define OFF_M  138240
#define OFF_SN 155648
#define LDS_TOTAL 155904

template<bool BF16W>
__global__ __launch_bounds__(1024, 4)
void wattn(const float* __restrict__ x, const float* __restrict__ mask,
           const float* __restrict__ qw, const float* __restrict__ qb,
           const float* __restrict__ kw, const float* __restrict__ kb,
           const float* __restrict__ vw, const float* __restrict__ vb,
           const float* __restrict__ pw, const float* __restrict__ pb,
           const short* __restrict__ wsb, float* __restrict__ out)
{
  __shared__ __align__(16) char smem[LDS_TOTAL];
  const int tid  = threadIdx.x;
  const int lane = tid & 63;
  const int w    = tid >> 6;     // wave 0..15
  const int c    = lane & 15;
  const int g    = lane >> 4;    // 0..3
  const int b    = blockIdx.x;

  const float* xg = x + (size_t)b * 16384;

  short* XN = (short*)(smem + OFF_XN);
  short* Qs = (short*)(smem + OFF_Q);
  short* Ks = (short*)(smem + OFF_K);
  short* Vs = (short*)(smem + OFF_V);
  float* ML = (float*)(smem + OFF_M);
  float* SN = (float*)(smem + OFF_SN);
  short* AN = (short*)(smem + OFF_K);

  const short* wq_bf = wsb;
  const short* wk_bf = wsb + 65536;
  const short* wv_bf = wsb + 131072;
  const short* wp_bf = wsb + 196608;

  auto wfragG = [&](const short* wb, const float* wf, int row, int k0) -> s16x8 {
    s16x8 r;
    if constexpr (BF16W) {
      r = *(const s16x8*)(wb + row * 256 + k0);
    } else {
      const f32x4* p = (const f32x4*)(wf + row * 256 + k0);
      f32x4 a = p[0], b2 = p[1];
#pragma unroll
      for (int j = 0; j < 4; ++j) { r[j] = f2bf(a[j] * GAIN); r[j+4] = f2bf(b2[j] * GAIN); }
    }
    return r;
  };

  // ---- P0: x -> row norms + normalized bf16 XN ----
  {
    const int row = tid >> 4;     // 0..63
    const int j   = tid & 15;
    f32x4 xv[4];
    float ss = 0.f;
#pragma unroll
    for (int u = 0; u < 4; ++u) {
      xv[u] = *(const f32x4*)(xg + row * 256 + (u * 16 + j) * 4);
      ss += xv[u][0]*xv[u][0] + xv[u][1]*xv[u][1] + xv[u][2]*xv[u][2] + xv[u][3]*xv[u][3];
    }
#pragma unroll
    for (int d = 1; d < 16; d <<= 1) ss += __shfl_xor(ss, d, 64);
    float s = fmaxf(sqrtf(ss), 1e-12f);
    float inv = 1.0f / s;
    if (j == 0) SN[row] = s;
#pragma unroll
    for (int u = 0; u < 4; ++u) {
      s16x4 pk;
#pragma unroll
      for (int e = 0; e < 4; ++e) pk[e] = f2bf(xv[u][e] * inv);
      *(s16x4*)(XN + row * 264 + (u * 16 + j) * 4) = pk;
    }
  }
  __syncthreads();

  // ---- P1: projections (waves 0-3: Q, 4-7: K, 8-11: V, 12-15: mask copy) ----
  {
    const int role = w >> 2;
    const int jj   = w & 3;
    if (role < 2) {
      const short* wb   = role ? wk_bf : wq_bf;
      const float* wf   = role ? kw : qw;
      const float* bias = role ? kb : qb;
      short* DST        = role ? Ks : Qs;
      const int d0 = jj * 64;
      f32x4 acc[4][4] = {};
#pragma unroll
      for (int kk = 0; kk < 8; ++kk) {
        const int k0 = kk * 32 + g * 8;
        s16x8 bf4[4];
#pragma unroll
        for (int ni = 0; ni < 4; ++ni) bf4[ni] = *(const s16x8*)(XN + (16*ni + c) * 264 + k0);
#pragma unroll
        for (int mi = 0; mi < 4; ++mi) {
          s16x8 af = wfragG(wb, wf, d0 + 16*mi + c, k0);
#pragma unroll
          for (int ni = 0; ni < 4; ++ni)
            acc[mi][ni] = __builtin_amdgcn_mfma_f32_16x16x32_bf16(af, bf4[ni], acc[mi][ni], 0, 0, 0);
        }
      }
      // D: col=token=16ni+c, row=d=d0+16mi+4g+r -> store token-major [token][d]
#pragma unroll
      for (int mi = 0; mi < 4; ++mi) {
        float bq[4];
#pragma unroll
        for (int r = 0; r < 4; ++r) bq[r] = bias[d0 + 16*mi + 4*g + r];
#pragma unroll
        for (int ni = 0; ni < 4; ++ni) {
          s16x4 pk;
#pragma unroll
          for (int r = 0; r < 4; ++r) pk[r] = f2bf(acc[mi][ni][r] + bq[r]);
          *(s16x4*)(DST + (16*ni + c) * 264 + d0 + 16*mi + 4*g) = pk;
        }
      }
    } else if (role == 2) {
      const int d0 = jj * 64;
      f32x4 acc[4][4] = {};   // [token tile][d tile]
#pragma unroll
      for (int kk = 0; kk < 8; ++kk) {
        const int k0 = kk * 32 + g * 8;
        s16x8 af4[4];
#pragma unroll
        for (int mi = 0; mi < 4; ++mi) af4[mi] = *(const s16x8*)(XN + (16*mi + c) * 264 + k0);
#pragma unroll
        for (int ni = 0; ni < 4; ++ni) {
          s16x8 bf = wfragG(wv_bf, vw, d0 + 16*ni + c, k0);
#pragma unroll
          for (int mi = 0; mi < 4; ++mi)
            acc[mi][ni] = __builtin_amdgcn_mfma_f32_16x16x32_bf16(af4[mi], bf, acc[mi][ni], 0, 0, 0);
        }
      }
      // D: col=d=d0+16ni+c, row=token=16mi+4g+r; un-normalize by snorm[token], store V^T[d][token]
      float bvv[4];
#pragma unroll
      for (int ni = 0; ni < 4; ++ni) bvv[ni] = vb[d0 + 16*ni + c];
#pragma unroll
      for (int mi = 0; mi < 4; ++mi) {
        float snr[4];
#pragma unroll
        for (int r = 0; r < 4; ++r) snr[r] = SN[16*mi + 4*g + r];
#pragma unroll
        for (int ni = 0; ni < 4; ++ni) {
          s16x4 pk;
#pragma unroll
          for (int r = 0; r < 4; ++r) pk[r] = f2bf(acc[mi][ni][r] * snr[r] + bvv[ni]);
          *(s16x4*)(Vs + (d0 + 16*ni + c) * 72 + 16*mi + 4*g) = pk;
        }
      }
    } else {
      // mask copy: 256 threads, 16KB
      const int u  = tid & 255;
      const int r0 = u >> 2, q4 = (u & 3) * 16;
      const f32x4* src = (const f32x4*)(mask + (size_t)b * 4096 + r0 * 64 + q4);
      f32x4* dst = (f32x4*)(ML + r0 * 68 + q4);
#pragma unroll
      for (int uu = 0; uu < 4; ++uu) dst[uu] = src[uu];
    }
  }
  __syncthreads();

  // ---- P2: QK^T + softmax; wave = (head h, row-half q2) ----
  const int h   = w >> 1;
  const int q2  = w & 1;
  const int qr0 = q2 * 32;
  short* Ph = (short*)(smem + (h < 7 ? h * 9216 : OFF_M));   // P[h]: [64][72] bf16

  f32x4 sacc[2][4];
  {
    s16x8 qf[2], kf[4];
#pragma unroll
    for (int mi = 0; mi < 2; ++mi) qf[mi] = *(const s16x8*)(Qs + (qr0 + 16*mi + c) * 264 + h*32 + g*8);
#pragma unroll
    for (int ni = 0; ni < 4; ++ni) kf[ni] = *(const s16x8*)(Ks + (16*ni + c) * 264 + h*32 + g*8);
    const f32x4 zf = {0.f, 0.f, 0.f, 0.f};
#pragma unroll
    for (int mi = 0; mi < 2; ++mi)
#pragma unroll
      for (int ni = 0; ni < 4; ++ni)
        sacc[mi][ni] = __builtin_amdgcn_mfma_f32_16x16x32_bf16(qf[mi], kf[ni], zf, 0, 0, 0);
  }
  __syncthreads();   // all Q/K reads done -> P (over XN/Q) and AN (over K) may be written

  {
    float mx[2][4], sm[2][4];
#pragma unroll
    for (int mi = 0; mi < 2; ++mi) {
#pragma unroll
      for (int r = 0; r < 4; ++r) mx[mi][r] = -1e30f;
#pragma unroll
      for (int ni = 0; ni < 4; ++ni)
#pragma unroll
        for (int r = 0; r < 4; ++r) {
          float l = sacc[mi][ni][r] * SCALE + ML[(qr0 + 16*mi + 4*g + r) * 68 + 16*ni + c];
          sacc[mi][ni][r] = l;
          mx[mi][r] = fmaxf(mx[mi][r], l);
        }
#pragma unroll
      for (int r = 0; r < 4; ++r)
#pragma unroll
        for (int d = 1; d < 16; d <<= 1) mx[mi][r] = fmaxf(mx[mi][r], __shfl_xor(mx[mi][r], d, 64));
#pragma unroll
      for (int r = 0; r < 4; ++r) sm[mi][r] = 0.f;
#pragma unroll
      for (int ni = 0; ni < 4; ++ni)
#pragma unroll
        for (int r = 0; r < 4; ++r) {
          float e = __expf(sacc[mi][ni][r] - mx[mi][r]);
          sacc[mi][ni][r] = e;
          sm[mi][r] += e;
        }
#pragma unroll
      for (int r = 0; r < 4; ++r)
#pragma unroll
        for (int d = 1; d < 16; d <<= 1) sm[mi][r] += __shfl_xor(sm[mi][r], d, 64);
    }
    __syncthreads();   // all ML reads done -> P[7] may overwrite ML
#pragma unroll
    for (int mi = 0; mi < 2; ++mi) {
      float rs[4];
#pragma unroll
      for (int r = 0; r < 4; ++r) rs[r] = 1.0f / sm[mi][r];
#pragma unroll
      for (int ni = 0; ni < 4; ++ni)
#pragma unroll
        for (int r = 0; r < 4; ++r)
          Ph[(qr0 + 16*mi + 4*g + r) * 72 + 16*ni + c] = f2bf(sacc[mi][ni][r] * rs[r]);
    }
  }

  // ---- P3: PV (reads own P rows, V^T) -> AN[token][d] over dead K ----
  {
    f32x4 pacc[2][2] = {};
#pragma unroll
    for (int kk = 0; kk < 2; ++kk) {
      const int k0 = kk * 32 + g * 8;
      s16x8 vf[2], pf[2];
#pragma unroll
      for (int mi = 0; mi < 2; ++mi) vf[mi] = *(const s16x8*)(Vs + (h*32 + 16*mi + c) * 72 + k0);
#pragma unroll
      for (int ni = 0; ni < 2; ++ni) pf[ni] = *(const s16x8*)(Ph + (qr0 + 16*ni + c) * 72 + k0);
#pragma unroll
      for (int mi = 0; mi < 2; ++mi)
#pragma unroll
        for (int ni = 0; ni < 2; ++ni)
          pacc[mi][ni] = __builtin_amdgcn_mfma_f32_16x16x32_bf16(vf[mi], pf[ni], pacc[mi][ni], 0, 0, 0);
    }
    // D: col=token=qr0+16ni+c, row=d=h*32+16mi+4g+r
#pragma unroll
    for (int mi = 0; mi < 2; ++mi)
#pragma unroll
      for (int ni = 0; ni < 2; ++ni) {
        s16x4 pk;
#pragma unroll
        for (int r = 0; r < 4; ++r) pk[r] = f2bf(pacc[mi][ni][r]);
        *(s16x4*)(AN + (qr0 + 16*ni + c) * 264 + h*32 + 16*mi + 4*g) = pk;
      }
  }
  __syncthreads();

  // ---- P4: final projection, wave w -> out cols 16w..16w+15 ----
  {
    const int o0 = w * 16;
    f32x4 facc[4] = {};
#pragma unroll
    for (int kk = 0; kk < 8; ++kk) {
      const int k0 = kk * 32 + g * 8;
      s16x8 bfw = wfragG(wp_bf, pw, o0 + c, k0);
#pragma unroll
      for (int mi = 0; mi < 4; ++mi) {
        s16x8 af = *(const s16x8*)(AN + (16*mi + c) * 264 + k0);
        facc[mi] = __builtin_amdgcn_mfma_f32_16x16x32_bf16(af, bfw, facc[mi], 0, 0, 0);
      }
    }
    const float bp = pb[o0 + c];
    float* og = out + (size_t)b * 16384;
#pragma unroll
    for (int mi = 0; mi < 4; ++mi)
#pragma unroll
      for (int r = 0; r < 4; ++r)
        og[(16*mi + 4*g + r) * 256 + o0 + c] = facc[mi][r] + bp;
  }
}

extern "C" void kernel_launch(void* const* d_in, const int* in_sizes, int n_in,
                              void* d_out, int out_size, void* d_ws, size_t ws_size,
                              hipStream_t stream) {
  const float* x    = (const float*)d_in[0];
  const float* mask = (const float*)d_in[1];
  const float* qw   = (const float*)d_in[2];
  const float* qb   = (const float*)d_in[3];
  const float* kw   = (const float*)d_in[4];
  const float* kb   = (const float*)d_in[5];
  const float* vw   = (const float*)d_in[6];
  const float* vb   = (const float*)d_in[7];
  const float* pw   = (const float*)d_in[8];
  const float* pb   = (const float*)d_in[9];
  float* out = (float*)d_out;

  if (ws_size >= 4u * 65536u * sizeof(short)) {
    short* wsb = (short*)d_ws;
    prep_weights<<<256, 256, 0, stream>>>(qw, kw, vw, pw, wsb);
    wattn<true><<<4096, 1024, 0, stream>>>(x, mask, qw, qb, kw, kb, vw, vb, pw, pb, wsb, out);
  } else {
    wattn<false><<<4096, 1024, 0, stream>>>(x, mask, qw, qb, kw, kb, vw, vb, pw, pb, nullptr, out);
  }
}

// Round 4
// 446.458 us; speedup vs baseline: 1.8407x; 1.1144x over previous
//
#include <hip/hip_runtime.h>

#define SCALE 0.17677669529663687f   // 1/sqrt(32)
#define GAIN  0.0625f                // 1/sqrt(256)
#define LOG2E 1.4426950408889634f
#define C1    (0.17677669529663687f * 1.4426950408889634f)   // SCALE*log2e

typedef float f32x4 __attribute__((ext_vector_type(4)));
typedef short s16x8 __attribute__((ext_vector_type(8)));
typedef short s16x4 __attribute__((ext_vector_type(4)));

static __device__ __forceinline__ short f2bf(float f) {
  union { float f; unsigned u; } v; v.f = f;
  unsigned u = v.u;
  u += 0x7fffu + ((u >> 16) & 1u);   // RNE
  return (short)(u >> 16);
}

__global__ void prep_weights(const float* __restrict__ qw, const float* __restrict__ kw,
                             const float* __restrict__ vw, const float* __restrict__ pw,
                             short* __restrict__ wsb) {
  int i = blockIdx.x * 256 + threadIdx.x;   // 0..65535
  wsb[i]          = f2bf(qw[i] * GAIN);
  wsb[i + 65536]  = f2bf(kw[i] * GAIN);
  wsb[i + 131072] = f2bf(vw[i] * GAIN);
  wsb[i + 196608] = f2bf(pw[i] * GAIN);
}

// ---- LDS layout (bytes) ----
// XN/Q/K: bf16 [64 tokens][264]; V: bf16 [256 d][72 tok]; ML: f32 [64][68] (mask*log2e); SN f32[64]
// Aliases: P[h] [64][72] bf16 (9216B): h=0..6 at h*9216 (over dead XN+Q), h=7 over dead ML.
//          AN [64][264] over dead K.
#define OFF_XN 0
#define OFF_Q  33792
#define OFF_K  67584
#define OFF_V  101376
#define OFF_M  138240
#define OFF_SN 155648
#define LDS_TOTAL 155904

template<bool BF16W>
__global__ __launch_bounds__(1024, 4)
void wattn(const float* __restrict__ x, const float* __restrict__ mask,
           const float* __restrict__ qw, const float* __restrict__ qb,
           const float* __restrict__ kw, const float* __restrict__ kb,
           const float* __restrict__ vw, const float* __restrict__ vb,
           const float* __restrict__ pw, const float* __restrict__ pb,
           const short* __restrict__ wsb, float* __restrict__ out)
{
  __shared__ __align__(16) char smem[LDS_TOTAL];
  const int tid  = threadIdx.x;
  const int lane = tid & 63;
  const int w    = tid >> 6;     // wave 0..15
  const int c    = lane & 15;
  const int g    = lane >> 4;    // 0..3
  const int b    = blockIdx.x;

  const float* xg = x + (size_t)b * 16384;

  short* XN = (short*)(smem + OFF_XN);
  short* Qs = (short*)(smem + OFF_Q);
  short* Ks = (short*)(smem + OFF_K);
  short* Vs = (short*)(smem + OFF_V);
  float* ML = (float*)(smem + OFF_M);
  float* SN = (float*)(smem + OFF_SN);
  short* AN = (short*)(smem + OFF_K);

  const short* wq_bf = wsb;
  const short* wk_bf = wsb + 65536;
  const short* wv_bf = wsb + 131072;
  const short* wp_bf = wsb + 196608;

  auto wfragG = [&](const short* wb, const float* wf, int row, int k0) -> s16x8 {
    s16x8 r;
    if constexpr (BF16W) {
      r = *(const s16x8*)(wb + row * 256 + k0);
    } else {
      const f32x4* p = (const f32x4*)(wf + row * 256 + k0);
      f32x4 a = p[0], b2 = p[1];
#pragma unroll
      for (int j = 0; j < 4; ++j) { r[j] = f2bf(a[j] * GAIN); r[j+4] = f2bf(b2[j] * GAIN); }
    }
    return r;
  };

  // ---- P0: x -> row norms + normalized bf16 XN ----
  {
    const int row = tid >> 4;     // 0..63
    const int j   = tid & 15;
    f32x4 xv[4];
    float ss = 0.f;
#pragma unroll
    for (int u = 0; u < 4; ++u) {
      xv[u] = *(const f32x4*)(xg + row * 256 + (u * 16 + j) * 4);
      ss += xv[u][0]*xv[u][0] + xv[u][1]*xv[u][1] + xv[u][2]*xv[u][2] + xv[u][3]*xv[u][3];
    }
#pragma unroll
    for (int d = 1; d < 16; d <<= 1) ss += __shfl_xor(ss, d, 64);
    float s = fmaxf(sqrtf(ss), 1e-12f);
    float inv = 1.0f / s;
    if (j == 0) SN[row] = s;
#pragma unroll
    for (int u = 0; u < 4; ++u) {
      s16x4 pk;
#pragma unroll
      for (int e = 0; e < 4; ++e) pk[e] = f2bf(xv[u][e] * inv);
      *(s16x4*)(XN + row * 264 + (u * 16 + j) * 4) = pk;
    }
  }
  __syncthreads();

  // ---- P1: projections (waves 0-3: Q, 4-7: K, 8-11: V, 12-15: mask copy *log2e) ----
  {
    const int role = w >> 2;
    const int jj   = w & 3;
    if (role < 2) {
      const short* wb   = role ? wk_bf : wq_bf;
      const float* wf   = role ? kw : qw;
      const float* bias = role ? kb : qb;
      short* DST        = role ? Ks : Qs;
      const int d0 = jj * 64;
      f32x4 acc[4][4] = {};
#pragma unroll
      for (int kk = 0; kk < 8; ++kk) {
        const int k0 = kk * 32 + g * 8;
        s16x8 bf4[4];
#pragma unroll
        for (int ni = 0; ni < 4; ++ni) bf4[ni] = *(const s16x8*)(XN + (16*ni + c) * 264 + k0);
#pragma unroll
        for (int mi = 0; mi < 4; ++mi) {
          s16x8 af = wfragG(wb, wf, d0 + 16*mi + c, k0);
#pragma unroll
          for (int ni = 0; ni < 4; ++ni)
            acc[mi][ni] = __builtin_amdgcn_mfma_f32_16x16x32_bf16(af, bf4[ni], acc[mi][ni], 0, 0, 0);
        }
      }
      // D: col=token=16ni+c, row=d=d0+16mi+4g+r -> store token-major [token][d]
#pragma unroll
      for (int mi = 0; mi < 4; ++mi) {
        float bq[4];
#pragma unroll
        for (int r = 0; r < 4; ++r) bq[r] = bias[d0 + 16*mi + 4*g + r];
#pragma unroll
        for (int ni = 0; ni < 4; ++ni) {
          s16x4 pk;
#pragma unroll
          for (int r = 0; r < 4; ++r) pk[r] = f2bf(acc[mi][ni][r] + bq[r]);
          *(s16x4*)(DST + (16*ni + c) * 264 + d0 + 16*mi + 4*g) = pk;
        }
      }
    } else if (role == 2) {
      const int d0 = jj * 64;
      f32x4 acc[4][4] = {};   // [token tile][d tile]
#pragma unroll
      for (int kk = 0; kk < 8; ++kk) {
        const int k0 = kk * 32 + g * 8;
        s16x8 af4[4];
#pragma unroll
        for (int mi = 0; mi < 4; ++mi) af4[mi] = *(const s16x8*)(XN + (16*mi + c) * 264 + k0);
#pragma unroll
        for (int ni = 0; ni < 4; ++ni) {
          s16x8 bf = wfragG(wv_bf, vw, d0 + 16*ni + c, k0);
#pragma unroll
          for (int mi = 0; mi < 4; ++mi)
            acc[mi][ni] = __builtin_amdgcn_mfma_f32_16x16x32_bf16(af4[mi], bf, acc[mi][ni], 0, 0, 0);
        }
      }
      // D: col=d=d0+16ni+c, row=token=16mi+4g+r; un-normalize by snorm[token], store V^T[d][token]
      float bvv[4];
#pragma unroll
      for (int ni = 0; ni < 4; ++ni) bvv[ni] = vb[d0 + 16*ni + c];
#pragma unroll
      for (int mi = 0; mi < 4; ++mi) {
        float snr[4];
#pragma unroll
        for (int r = 0; r < 4; ++r) snr[r] = SN[16*mi + 4*g + r];
#pragma unroll
        for (int ni = 0; ni < 4; ++ni) {
          s16x4 pk;
#pragma unroll
          for (int r = 0; r < 4; ++r) pk[r] = f2bf(acc[mi][ni][r] * snr[r] + bvv[ni]);
          *(s16x4*)(Vs + (d0 + 16*ni + c) * 72 + 16*mi + 4*g) = pk;
        }
      }
    } else {
      // mask copy (scaled by log2e): 256 threads, 16KB
      const int u  = tid & 255;
      const int r0 = u >> 2, q4 = (u & 3) * 16;
      const f32x4* src = (const f32x4*)(mask + (size_t)b * 4096 + r0 * 64 + q4);
      f32x4* dst = (f32x4*)(ML + r0 * 68 + q4);
#pragma unroll
      for (int uu = 0; uu < 4; ++uu) dst[uu] = src[uu] * LOG2E;
    }
  }
  __syncthreads();

  // ---- P2: S^T = K·Q^T (D: col=q-token, row=key); wave = (head h, row-half q2) ----
  const int h   = w >> 1;
  const int q2  = w & 1;
  const int qr0 = q2 * 32;
  short* Ph = (short*)(smem + (h < 7 ? h * 9216 : OFF_M));   // P[h]: [64][72] bf16

  f32x4 sacc[4][2];
  {
    s16x8 kf[4], qf[2];
#pragma unroll
    for (int mi = 0; mi < 4; ++mi) kf[mi] = *(const s16x8*)(Ks + (16*mi + c) * 264 + h*32 + g*8);
#pragma unroll
    for (int ni = 0; ni < 2; ++ni) qf[ni] = *(const s16x8*)(Qs + (qr0 + 16*ni + c) * 264 + h*32 + g*8);
    const f32x4 zf = {0.f, 0.f, 0.f, 0.f};
#pragma unroll
    for (int mi = 0; mi < 4; ++mi)
#pragma unroll
      for (int ni = 0; ni < 2; ++ni)
        sacc[mi][ni] = __builtin_amdgcn_mfma_f32_16x16x32_bf16(kf[mi], qf[ni], zf, 0, 0, 0);
  }
  __syncthreads();   // all Q/K reads done -> P (over XN/Q) and AN (over K) may be written

  // ---- softmax without max-subtraction (logits bounded; exp2-folded) ----
  float rs[2];
  {
    float sm[2] = {0.f, 0.f};
#pragma unroll
    for (int mi = 0; mi < 4; ++mi)
#pragma unroll
      for (int ni = 0; ni < 2; ++ni) {
        f32x4 mlv = *(const f32x4*)(ML + (qr0 + 16*ni + c) * 68 + 16*mi + 4*g);
#pragma unroll
        for (int r = 0; r < 4; ++r) {
          float e = exp2f(sacc[mi][ni][r] * C1 + mlv[r]);
          sacc[mi][ni][r] = e;
          sm[ni] += e;
        }
      }
#pragma unroll
    for (int ni = 0; ni < 2; ++ni) {
      sm[ni] += __shfl_xor(sm[ni], 16, 64);
      sm[ni] += __shfl_xor(sm[ni], 32, 64);
      rs[ni] = 1.0f / sm[ni];
    }
  }
  __syncthreads();   // all ML reads done -> P[7] may overwrite ML

  // ---- P write: lane holds 4 consecutive keys per reg-quad -> b64 stores ----
#pragma unroll
  for (int ni = 0; ni < 2; ++ni)
#pragma unroll
    for (int mi = 0; mi < 4; ++mi) {
      s16x4 pk;
#pragma unroll
      for (int r = 0; r < 4; ++r) pk[r] = f2bf(sacc[mi][ni][r] * rs[ni]);
      *(s16x4*)(Ph + (qr0 + 16*ni + c) * 72 + 16*mi + 4*g) = pk;
    }

  // ---- P3: PV (reads own P rows, V^T) -> AN[token][d] over dead K ----
  {
    f32x4 pacc[2][2] = {};
#pragma unroll
    for (int kk = 0; kk < 2; ++kk) {
      const int k0 = kk * 32 + g * 8;
      s16x8 vf[2], pf[2];
#pragma unroll
      for (int mi = 0; mi < 2; ++mi) vf[mi] = *(const s16x8*)(Vs + (h*32 + 16*mi + c) * 72 + k0);
#pragma unroll
      for (int ni = 0; ni < 2; ++ni) pf[ni] = *(const s16x8*)(Ph + (qr0 + 16*ni + c) * 72 + k0);
#pragma unroll
      for (int mi = 0; mi < 2; ++mi)
#pragma unroll
        for (int ni = 0; ni < 2; ++ni)
          pacc[mi][ni] = __builtin_amdgcn_mfma_f32_16x16x32_bf16(vf[mi], pf[ni], pacc[mi][ni], 0, 0, 0);
    }
    // D: col=token=qr0+16ni+c, row=d=h*32+16mi+4g+r
#pragma unroll
    for (int mi = 0; mi < 2; ++mi)
#pragma unroll
      for (int ni = 0; ni < 2; ++ni) {
        s16x4 pk;
#pragma unroll
        for (int r = 0; r < 4; ++r) pk[r] = f2bf(pacc[mi][ni][r]);
        *(s16x4*)(AN + (qr0 + 16*ni + c) * 264 + h*32 + 16*mi + 4*g) = pk;
      }
  }
  __syncthreads();

  // ---- P4: final projection, wave w -> out cols 16w..16w+15 ----
  {
    const int o0 = w * 16;
    f32x4 facc[4] = {};
#pragma unroll
    for (int kk = 0; kk < 8; ++kk) {
      const int k0 = kk * 32 + g * 8;
      s16x8 bfw = wfragG(wp_bf, pw, o0 + c, k0);
#pragma unroll
      for (int mi = 0; mi < 4; ++mi) {
        s16x8 af = *(const s16x8*)(AN + (16*mi + c) * 264 + k0);
        facc[mi] = __builtin_amdgcn_mfma_f32_16x16x32_bf16(af, bfw, facc[mi], 0, 0, 0);
      }
    }
    const float bp = pb[o0 + c];
    float* og = out + (size_t)b * 16384;
#pragma unroll
    for (int mi = 0; mi < 4; ++mi)
#pragma unroll
      for (int r = 0; r < 4; ++r)
        og[(16*mi + 4*g + r) * 256 + o0 + c] = facc[mi][r] + bp;
  }
}

extern "C" void kernel_launch(void* const* d_in, const int* in_sizes, int n_in,
                              void* d_out, int out_size, void* d_ws, size_t ws_size,
                              hipStream_t stream) {
  const float* x    = (const float*)d_in[0];
  const float* mask = (const float*)d_in[1];
  const float* qw   = (const float*)d_in[2];
  const float* qb   = (const float*)d_in[3];
  const float* kw   = (const float*)d_in[4];
  const float* kb   = (const float*)d_in[5];
  const float* vw   = (const float*)d_in[6];
  const float* vb   = (const float*)d_in[7];
  const float* pw   = (const float*)d_in[8];
  const float* pb   = (const float*)d_in[9];
  float* out = (float*)d_out;

  if (ws_size >= 4u * 65536u * sizeof(short)) {
    short* wsb = (short*)d_ws;
    prep_weights<<<256, 256, 0, stream>>>(qw, kw, vw, pw, wsb);
    wattn<true><<<4096, 1024, 0, stream>>>(x, mask, qw, qb, kw, kb, vw, vb, pw, pb, wsb, out);
  } else {
    wattn<false><<<4096, 1024, 0, stream>>>(x, mask, qw, qb, kw, kb, vw, vb, pw, pb, nullptr, out);
  }
}